// Round 1
// baseline (432.200 us; speedup 1.0000x reference)
//
#include <hip/hip_runtime.h>

typedef _Float16 f16;
typedef _Float16 f16x2 __attribute__((ext_vector_type(2)));
typedef _Float16 f16x4 __attribute__((ext_vector_type(4)));
typedef _Float16 f16x8 __attribute__((ext_vector_type(8)));
typedef float    f32x2 __attribute__((ext_vector_type(2)));
typedef float    f32x4 __attribute__((ext_vector_type(4)));

// async global->LDS, 16B per lane; LDS dest = wave-uniform base + lane*16
#define GLDS16(gptr, lptr)                                                     \
  __builtin_amdgcn_global_load_lds(                                            \
      (const __attribute__((address_space(1))) void*)(gptr),                   \
      (__attribute__((address_space(3))) void*)(lptr), 16, 0, 0)

// ---------------- fp32 -> f16 cast (vectorized) ----------------
__global__ __launch_bounds__(256) void k_cast(const float* __restrict__ in,
                                              f16* __restrict__ out, int n4) {
  int i = blockIdx.x * 256 + threadIdx.x;
  if (i >= n4) return;
  f32x4 v = ((const f32x4*)in)[i];
  f16x4 h;
  h[0] = (f16)v[0]; h[1] = (f16)v[1]; h[2] = (f16)v[2]; h[3] = (f16)v[3];
  ((f16x4*)out)[i] = h;
}

// ---------------- GEMM  C[M,N] = A[M,K] * B[N,K]^T  (both row-major f16) ----
// 128x128 tile / block of 256 threads (4 waves, 2x2), BK=32, mfma 16x16x32 f16
__global__ __launch_bounds__(256) void k_gemm_bt(const f16* __restrict__ A,
                                                 const f16* __restrict__ B,
                                                 void* __restrict__ Cout,
                                                 int M, int N, int K,
                                                 int out_is_f16) {
  __shared__ f16 sA[128 * 32];
  __shared__ f16 sB[128 * 32];
  const int tid = threadIdx.x;
  const int wave = tid >> 6, lane = tid & 63;
  const int lr = lane & 15, lq = lane >> 4;
  const int wm = (wave >> 1) * 64, wn = (wave & 1) * 64;
  const size_t m0 = (size_t)blockIdx.x * 128, n0 = (size_t)blockIdx.y * 128;

  f32x4 acc[4][4] = {};

  const f16* ga = A + (m0 + (tid >> 2)) * (size_t)K + (tid & 3) * 8;
  const f16* gb = B + (n0 + (tid >> 2)) * (size_t)K + (tid & 3) * 8;

  for (int k0 = 0; k0 < K; k0 += 32) {
    __syncthreads();  // previous iter's LDS reads complete
#pragma unroll
    for (int r = 0; r < 2; ++r) {
      GLDS16(ga + (size_t)(r * 64) * K + k0, (char*)sA + r * 4096 + wave * 1024);
      GLDS16(gb + (size_t)(r * 64) * K + k0, (char*)sB + r * 4096 + wave * 1024);
    }
    __syncthreads();  // vmcnt(0) drain before barrier -> staged data visible

    f16x8 af[4], bf[4];
#pragma unroll
    for (int i = 0; i < 4; ++i)
      af[i] = *(const f16x8*)&sA[(wm + i * 16 + lr) * 32 + lq * 8];
#pragma unroll
    for (int j = 0; j < 4; ++j)
      bf[j] = *(const f16x8*)&sB[(wn + j * 16 + lr) * 32 + lq * 8];
#pragma unroll
    for (int i = 0; i < 4; ++i)
#pragma unroll
      for (int j = 0; j < 4; ++j)
        acc[i][j] = __builtin_amdgcn_mfma_f32_16x16x32_f16(af[i], bf[j],
                                                           acc[i][j], 0, 0, 0);
  }

  // epilogue: C layout col=lane&15, row=quad*4+reg
  if (out_is_f16) {
    f16* C = (f16*)Cout;
#pragma unroll
    for (int i = 0; i < 4; ++i)
#pragma unroll
      for (int j = 0; j < 4; ++j)
#pragma unroll
        for (int r = 0; r < 4; ++r)
          C[(m0 + wm + i * 16 + lq * 4 + r) * (size_t)N + n0 + wn + j * 16 + lr] =
              (f16)acc[i][j][r];
  } else {
    float* C = (float*)Cout;
#pragma unroll
    for (int i = 0; i < 4; ++i)
#pragma unroll
      for (int j = 0; j < 4; ++j)
#pragma unroll
        for (int r = 0; r < 4; ++r)
          C[(m0 + wm + i * 16 + lq * 4 + r) * (size_t)N + n0 + wn + j * 16 + lr] =
              acc[i][j][r];
  }
}

// ---------------- RoPE + head-split for Q,K -> (B,H,T,64) f16 ----------------
__global__ __launch_bounds__(256) void k_rope(const f16* __restrict__ qkv,
                                              const float* __restrict__ rope,
                                              f16* __restrict__ qh,
                                              f16* __restrict__ kh) {
  int idx = blockIdx.x * 256 + threadIdx.x;  // b*2^21 + t*1024 + pair
  int pair = idx & 1023, t = (idx >> 10) & 2047, b = idx >> 21;
  int which = pair >> 9, p = pair & 511;
  const f16* src = qkv + ((size_t)(b * 2048 + t)) * 3072 + which * 1024 + p * 2;
  f16x2 s2 = *(const f16x2*)src;
  float xr = (float)s2[0], xi = (float)s2[1];
  f32x2 cs = *(const f32x2*)(rope + ((size_t)t * 512 + p) * 2);
  float rr = xr * cs[0] - xi * cs[1];
  float ri = xr * cs[1] + xi * cs[0];
  int h = p >> 5, cc = (p & 31) * 2;
  f16* dst = (which ? kh : qh) + ((size_t)(b * 16 + h) * 2048 + t) * 64 + cc;
  f16x2 o; o[0] = (f16)rr; o[1] = (f16)ri;
  *(f16x2*)dst = o;
}

// ---------------- V transpose-cast -> (B,H,64,T) f16 ----------------
__global__ __launch_bounds__(256) void k_transpv(const f16* __restrict__ qkv,
                                                 f16* __restrict__ vt) {
  int bh = blockIdx.x >> 5, tt = blockIdx.x & 31;
  int b = bh >> 4, h = bh & 15;
  __shared__ f16 tile[64][65];
  int tid = threadIdx.x;
  int r = tid >> 4, c4 = (tid & 15) * 4;
#pragma unroll
  for (int rr = 0; rr < 4; ++rr) {
    int row = rr * 16 + r;  // t within tile
    const f16* src =
        qkv + ((size_t)(b * 2048 + tt * 64 + row)) * 3072 + 2048 + h * 64 + c4;
    f16x4 v = *(const f16x4*)src;
    tile[row][c4 + 0] = v[0]; tile[row][c4 + 1] = v[1];
    tile[row][c4 + 2] = v[2]; tile[row][c4 + 3] = v[3];
  }
  __syncthreads();
#pragma unroll
  for (int rr = 0; rr < 4; ++rr) {
    int c = rr * 16 + r;          // dk col
    int t4 = (tid & 15) * 4;      // t within tile
    f16x4 o;
    o[0] = tile[t4 + 0][c]; o[1] = tile[t4 + 1][c];
    o[2] = tile[t4 + 2][c]; o[3] = tile[t4 + 3][c];
    *(f16x4*)(vt + ((size_t)(bh * 64 + c)) * 2048 + tt * 64 + t4) = o;
  }
}

// ---------------- Flash attention ----------------
// block: one (bh, 64-row q-tile); wave w owns q columns w*16 + (lane&15).
// S^T = K·Q^T via mfma 16x16x32 (C-layout row=kv, col=q)
// P^T (C-layout) feeds mfma_16x16x16f16 B-operand DIRECTLY (layouts coincide).
// O^T = V^T·P^T accumulated; epilogue normalizes and writes (B,T,H*64) f16.
__global__ __launch_bounds__(256) void k_attn(const f16* __restrict__ Qp,
                                              const f16* __restrict__ Kp,
                                              const f16* __restrict__ Vt,
                                              f16* __restrict__ Op) {
  __shared__ f16 sQ[64 * 64];    // 8 KB
  __shared__ f16 sK[128 * 64];   // 16 KB
  __shared__ f16 sV[64 * 128];   // 16 KB  (dk-major: sV[c*128 + t])
  const int tid = threadIdx.x, wave = tid >> 6, lane = tid & 63;
  const int lr = lane & 15, lq = lane >> 4;
  const int bh = blockIdx.x, qt = blockIdx.y;
  const size_t base = (size_t)bh * 2048 * 64;

  // stage Q tile (rows qt*64..+64 contiguous)
  const f16* gq = Qp + base + (size_t)qt * 64 * 64;
#pragma unroll
  for (int r = 0; r < 2; ++r)
    GLDS16(gq + r * 2048 + tid * 8, (char*)sQ + r * 4096 + wave * 1024);
  __syncthreads();
  f16x8 qf0 = *(const f16x8*)&sQ[(wave * 16 + lr) * 64 + lq * 8];
  f16x8 qf1 = *(const f16x8*)&sQ[(wave * 16 + lr) * 64 + 32 + lq * 8];

  f32x4 ot[4] = {};
  float m_i = -__builtin_inff(), l_i = 0.f;
  const float sc = 0.125f * 1.44269504088896f;  // 1/sqrt(64) * log2(e)

  for (int jc = 0; jc < 16; ++jc) {
    __syncthreads();  // previous chunk's LDS reads done
    const f16* gk = Kp + base + (size_t)jc * 128 * 64;
    const f16* gv = Vt + base + (size_t)jc * 128;
#pragma unroll
    for (int r = 0; r < 4; ++r) {
      GLDS16(gk + r * 2048 + tid * 8, (char*)sK + r * 4096 + wave * 1024);
      GLDS16(gv + (size_t)(r * 16 + (tid >> 4)) * 2048 + (tid & 15) * 8,
             (char*)sV + r * 4096 + wave * 1024);
    }
    __syncthreads();  // staged data visible

    // S^T tiles: st[nt] covers kv rows nt*16 + lq*4 + r, q col = lr
    f32x4 st[8];
#pragma unroll
    for (int nt = 0; nt < 8; ++nt) {
      f16x8 kf0 = *(const f16x8*)&sK[(nt * 16 + lr) * 64 + lq * 8];
      f16x8 kf1 = *(const f16x8*)&sK[(nt * 16 + lr) * 64 + 32 + lq * 8];
      f32x4 s = {0.f, 0.f, 0.f, 0.f};
      s = __builtin_amdgcn_mfma_f32_16x16x32_f16(kf0, qf0, s, 0, 0, 0);
      s = __builtin_amdgcn_mfma_f32_16x16x32_f16(kf1, qf1, s, 0, 0, 0);
      st[nt] = s;
    }

    // online softmax (log2 domain), per q-column = per lane-group {lr,+16,+32,+48}
    float mloc = -__builtin_inff();
#pragma unroll
    for (int nt = 0; nt < 8; ++nt)
#pragma unroll
      for (int r = 0; r < 4; ++r) mloc = fmaxf(mloc, st[nt][r]);
    mloc *= sc;
    mloc = fmaxf(mloc, __shfl_xor(mloc, 16));
    mloc = fmaxf(mloc, __shfl_xor(mloc, 32));
    float mnew = fmaxf(m_i, mloc);
    float alpha = exp2f(m_i - mnew);
    float lsum = 0.f;
    f16x4 pf[8];
#pragma unroll
    for (int nt = 0; nt < 8; ++nt) {
#pragma unroll
      for (int r = 0; r < 4; ++r) {
        float p = exp2f(st[nt][r] * sc - mnew);
        lsum += p;
        pf[nt][r] = (f16)p;
      }
    }
    lsum += __shfl_xor(lsum, 16);
    lsum += __shfl_xor(lsum, 32);
    l_i = l_i * alpha + lsum;
    m_i = mnew;
#pragma unroll
    for (int d = 0; d < 4; ++d) ot[d] *= alpha;

    // O^T += V^T · P^T  (A-frag from sV, B-frag = pf from registers)
#pragma unroll
    for (int d = 0; d < 4; ++d)
#pragma unroll
      for (int ks = 0; ks < 8; ++ks) {
        f16x4 vf = *(const f16x4*)&sV[(d * 16 + lr) * 128 + ks * 16 + lq * 4];
        ot[d] = __builtin_amdgcn_mfma_f32_16x16x16f16(vf, pf[ks], ot[d], 0, 0, 0);
      }
  }

  // epilogue: O[q][c] = ot[d][r] / l,  c = d*16 + lq*4 + r (contiguous in r)
  float rl = 1.f / l_i;
  int b = bh >> 4, h = bh & 15;
  int t = qt * 64 + wave * 16 + lr;
  f16* gout = Op + ((size_t)(b * 2048 + t)) * 1024 + h * 64;
#pragma unroll
  for (int d = 0; d < 4; ++d) {
    f16x4 o;
#pragma unroll
    for (int r = 0; r < 4; ++r) o[r] = (f16)(ot[d][r] * rl);
    *(f16x4*)&gout[d * 16 + lq * 4] = o;
  }
}

// ---------------- launch ----------------
extern "C" void kernel_launch(void* const* d_in, const int* in_sizes, int n_in,
                              void* d_out, int out_size, void* d_ws,
                              size_t ws_size, hipStream_t stream) {
  const float* x     = (const float*)d_in[0];  // (2,2048,1024)
  const float* rope  = (const float*)d_in[1];  // (2048,512,2)
  const float* wqkv  = (const float*)d_in[2];  // (3072,1024)
  const float* wproj = (const float*)d_in[3];  // (1024,1024)
  float* out = (float*)d_out;                  // (2,2048,1024) fp32

  char* w = (char*)d_ws;
  const size_t MB = 1024 * 1024;
  f16* xh   = (f16*)(w + 0);        // 8 MB (dead after gemm1)
  f16* qh   = (f16*)(w + 0);        // 8 MB (reuses xh region)
  f16* wqh  = (f16*)(w + 8 * MB);   // 6 MB
  f16* wph  = (f16*)(w + 14 * MB);  // 2 MB
  f16* qkvh = (f16*)(w + 16 * MB);  // 24 MB (dead after rope/transpv)
  f16* aoh  = (f16*)(w + 16 * MB);  // 8 MB (reuses qkvh region)
  f16* kh   = (f16*)(w + 40 * MB);  // 8 MB
  f16* vth  = (f16*)(w + 48 * MB);  // 8 MB  -> total 56 MB

  k_cast<<<4096, 256, 0, stream>>>(x, xh, 1048576);
  k_cast<<<3072, 256, 0, stream>>>(wqkv, wqh, 786432);
  k_cast<<<1024, 256, 0, stream>>>(wproj, wph, 262144);

  // qkv = x @ w_qkv^T : (4096,3072) f16
  k_gemm_bt<<<dim3(32, 24), 256, 0, stream>>>(xh, wqh, (void*)qkvh, 4096, 3072,
                                              1024, 1);
  // rope + head split q,k ; transpose v
  k_rope<<<16384, 256, 0, stream>>>(qkvh, rope, qh, kh);
  k_transpv<<<1024, 256, 0, stream>>>(qkvh, vth);

  // attention -> (B,T,H*64) f16
  k_attn<<<dim3(32, 32), 256, 0, stream>>>(qh, kh, vth, aoh);

  // out = attn @ w_proj^T : (4096,1024) fp32
  k_gemm_bt<<<dim3(32, 8), 256, 0, stream>>>(aoh, wph, (void*)out, 4096, 1024,
                                             1024, 0);
}

// Round 2
// 241.359 us; speedup vs baseline: 1.7907x; 1.7907x over previous
//
#include <hip/hip_runtime.h>

typedef _Float16 f16;
typedef _Float16 f16x2 __attribute__((ext_vector_type(2)));
typedef _Float16 f16x4 __attribute__((ext_vector_type(4)));
typedef _Float16 f16x8 __attribute__((ext_vector_type(8)));
typedef float    f32x2 __attribute__((ext_vector_type(2)));
typedef float    f32x4 __attribute__((ext_vector_type(4)));

// async global->LDS, 16B per lane; LDS dest = wave-uniform base + lane*16
#define GLDS16(gptr, lptr)                                                     \
  __builtin_amdgcn_global_load_lds(                                            \
      (const __attribute__((address_space(1))) void*)(gptr),                   \
      (__attribute__((address_space(3))) void*)(lptr), 16, 0, 0)

// ---------------- fp32 -> f16 cast (vectorized) ----------------
__global__ __launch_bounds__(256) void k_cast(const float* __restrict__ in,
                                              f16* __restrict__ out, int n4) {
  int i = blockIdx.x * 256 + threadIdx.x;
  if (i >= n4) return;
  f32x4 v = ((const f32x4*)in)[i];
  f16x4 h;
  h[0] = (f16)v[0]; h[1] = (f16)v[1]; h[2] = (f16)v[2]; h[3] = (f16)v[3];
  ((f16x4*)out)[i] = h;
}

// ---------------- GEMM  C[M,N] = A[M,K] * B[N,K]^T  (both row-major f16) ----
// 128x128 tile / block of 256 threads (4 waves, 2x2), BK=32, mfma 16x16x32 f16
// LDS rows = 32 f16 = 4 granules of 16B; granule g of row r stored at slot
// g ^ ((r>>1)&3)  (row bit0 already contributes 16 banks; bits1-2 via XOR).
__global__ __launch_bounds__(256) void k_gemm_bt(const f16* __restrict__ A,
                                                 const f16* __restrict__ B,
                                                 void* __restrict__ Cout,
                                                 int M, int N, int K,
                                                 int out_is_f16) {
  __shared__ f16 sA[128 * 32];
  __shared__ f16 sB[128 * 32];
  const int tid = threadIdx.x;
  const int wave = tid >> 6, lane = tid & 63;
  const int lr = lane & 15, lq = lane >> 4;
  const int wm = (wave >> 1) * 64, wn = (wave & 1) * 64;
  const size_t m0 = (size_t)blockIdx.x * 128, n0 = (size_t)blockIdx.y * 128;

  f32x4 acc[4][4] = {};

  // staging: lane writes LDS slot (row = r*64 + tid>>2, g' = tid&3);
  // fetch global granule g = g' ^ ((row>>1)&3), (row>>1)&3 == (tid>>3)&3
  const int gsw = ((tid & 3) ^ ((tid >> 3) & 3)) * 8;
  const f16* ga = A + (m0 + (tid >> 2)) * (size_t)K + gsw;
  const f16* gb = B + (n0 + (tid >> 2)) * (size_t)K + gsw;

  const int swr = (lr >> 1) & 3;  // read-side xor key per fragment row

  for (int k0 = 0; k0 < K; k0 += 32) {
    __syncthreads();  // previous iter's LDS reads complete
#pragma unroll
    for (int r = 0; r < 2; ++r) {
      GLDS16(ga + (size_t)(r * 64) * K + k0, (char*)sA + r * 4096 + wave * 1024);
      GLDS16(gb + (size_t)(r * 64) * K + k0, (char*)sB + r * 4096 + wave * 1024);
    }
    __syncthreads();  // vmcnt(0) drain before barrier -> staged data visible

    f16x8 af[4], bf[4];
#pragma unroll
    for (int i = 0; i < 4; ++i)
      af[i] = *(const f16x8*)&sA[(wm + i * 16 + lr) * 32 + ((lq ^ swr) * 8)];
#pragma unroll
    for (int j = 0; j < 4; ++j)
      bf[j] = *(const f16x8*)&sB[(wn + j * 16 + lr) * 32 + ((lq ^ swr) * 8)];
#pragma unroll
    for (int i = 0; i < 4; ++i)
#pragma unroll
      for (int j = 0; j < 4; ++j)
        acc[i][j] = __builtin_amdgcn_mfma_f32_16x16x32_f16(af[i], bf[j],
                                                           acc[i][j], 0, 0, 0);
  }

  // epilogue: C layout col=lane&15, row=quad*4+reg
  if (out_is_f16) {
    f16* C = (f16*)Cout;
#pragma unroll
    for (int i = 0; i < 4; ++i)
#pragma unroll
      for (int j = 0; j < 4; ++j)
#pragma unroll
        for (int r = 0; r < 4; ++r)
          C[(m0 + wm + i * 16 + lq * 4 + r) * (size_t)N + n0 + wn + j * 16 + lr] =
              (f16)acc[i][j][r];
  } else {
    float* C = (float*)Cout;
#pragma unroll
    for (int i = 0; i < 4; ++i)
#pragma unroll
      for (int j = 0; j < 4; ++j)
#pragma unroll
        for (int r = 0; r < 4; ++r)
          C[(m0 + wm + i * 16 + lq * 4 + r) * (size_t)N + n0 + wn + j * 16 + lr] =
              acc[i][j][r];
  }
}

// ---------------- RoPE + head-split for Q,K -> (B,H,T,64) f16 ----------------
__global__ __launch_bounds__(256) void k_rope(const f16* __restrict__ qkv,
                                              const float* __restrict__ rope,
                                              f16* __restrict__ qh,
                                              f16* __restrict__ kh) {
  int idx = blockIdx.x * 256 + threadIdx.x;  // b*2^21 + t*1024 + pair
  int pair = idx & 1023, t = (idx >> 10) & 2047, b = idx >> 21;
  int which = pair >> 9, p = pair & 511;
  const f16* src = qkv + ((size_t)(b * 2048 + t)) * 3072 + which * 1024 + p * 2;
  f16x2 s2 = *(const f16x2*)src;
  float xr = (float)s2[0], xi = (float)s2[1];
  f32x2 cs = *(const f32x2*)(rope + ((size_t)t * 512 + p) * 2);
  float rr = xr * cs[0] - xi * cs[1];
  float ri = xr * cs[1] + xi * cs[0];
  int h = p >> 5, cc = (p & 31) * 2;
  f16* dst = (which ? kh : qh) + ((size_t)(b * 16 + h) * 2048 + t) * 64 + cc;
  f16x2 o; o[0] = (f16)rr; o[1] = (f16)ri;
  *(f16x2*)dst = o;
}

// ---------------- V transpose-cast -> (B,H,64,T) f16 ----------------
__global__ __launch_bounds__(256) void k_transpv(const f16* __restrict__ qkv,
                                                 f16* __restrict__ vt) {
  int bh = blockIdx.x >> 5, tt = blockIdx.x & 31;
  int b = bh >> 4, h = bh & 15;
  __shared__ f16 tile[64][65];
  int tid = threadIdx.x;
  int r = tid >> 4, c4 = (tid & 15) * 4;
#pragma unroll
  for (int rr = 0; rr < 4; ++rr) {
    int row = rr * 16 + r;  // t within tile
    const f16* src =
        qkv + ((size_t)(b * 2048 + tt * 64 + row)) * 3072 + 2048 + h * 64 + c4;
    f16x4 v = *(const f16x4*)src;
    tile[row][c4 + 0] = v[0]; tile[row][c4 + 1] = v[1];
    tile[row][c4 + 2] = v[2]; tile[row][c4 + 3] = v[3];
  }
  __syncthreads();
#pragma unroll
  for (int rr = 0; rr < 4; ++rr) {
    int c = rr * 16 + r;          // dk col
    int t4 = (tid & 15) * 4;      // t within tile
    f16x4 o;
    o[0] = tile[t4 + 0][c]; o[1] = tile[t4 + 1][c];
    o[2] = tile[t4 + 2][c]; o[3] = tile[t4 + 3][c];
    *(f16x4*)(vt + ((size_t)(bh * 64 + c)) * 2048 + tt * 64 + t4) = o;
  }
}

// ---------------- Flash attention ----------------
// block: one (bh, 64-row q-tile); wave w owns q columns w*16 + (lane&15).
// S^T = K·Q^T via mfma 16x16x32 (C-layout row=kv, col=q)
// P^T (C-layout) feeds mfma_16x16x16f16 B-operand DIRECTLY (layouts coincide).
// O^T = V^T·P^T accumulated; epilogue normalizes and writes (B,T,H*64) f16.
// LDS swizzle: sQ/sK rows = 64 f16 = 8 granules, slot = g ^ (row&7);
//              sV  rows = 128 f16 = 16 granules, slot = g ^ (row&15).
__global__ __launch_bounds__(256) void k_attn(const f16* __restrict__ Qp,
                                              const f16* __restrict__ Kp,
                                              const f16* __restrict__ Vt,
                                              f16* __restrict__ Op) {
  __shared__ f16 sQ[64 * 64];    // 8 KB
  __shared__ f16 sK[128 * 64];   // 16 KB
  __shared__ f16 sV[64 * 128];   // 16 KB  (dk-major: sV[c*128 + t])
  const int tid = threadIdx.x, wave = tid >> 6, lane = tid & 63;
  const int lr = lane & 15, lq = lane >> 4;
  const int bh = blockIdx.x, qt = blockIdx.y;
  const size_t base = (size_t)bh * 2048 * 64;

  // staging swizzle offsets (in f16 elements)
  const int sw8 = ((tid & 7) ^ ((tid >> 3) & 7)) * 8;    // sQ/sK granule xor
  const int sw16 = ((tid & 15) ^ ((tid >> 4) & 15)) * 8; // sV granule xor

  // stage Q tile (rows qt*64..+64 contiguous); row = r*32 + (tid>>3)
  const f16* gq = Qp + base + (size_t)qt * 64 * 64;
#pragma unroll
  for (int r = 0; r < 2; ++r)
    GLDS16(gq + (size_t)(r * 32 + (tid >> 3)) * 64 + sw8,
           (char*)sQ + r * 4096 + wave * 1024);
  __syncthreads();
  const int lr7 = lr & 7;
  f16x8 qf0 = *(const f16x8*)&sQ[(wave * 16 + lr) * 64 + ((lq ^ lr7) * 8)];
  f16x8 qf1 = *(const f16x8*)&sQ[(wave * 16 + lr) * 64 + (((4 + lq) ^ lr7) * 8)];

  f32x4 ot[4] = {};
  float m_i = -__builtin_inff(), l_i = 0.f;
  const float sc = 0.125f * 1.44269504088896f;  // 1/sqrt(64) * log2(e)

  for (int jc = 0; jc < 16; ++jc) {
    __syncthreads();  // previous chunk's LDS reads done
    const f16* gk = Kp + base + (size_t)jc * 128 * 64;
    const f16* gv = Vt + base + (size_t)jc * 128;
#pragma unroll
    for (int r = 0; r < 4; ++r) {
      GLDS16(gk + (size_t)(r * 32 + (tid >> 3)) * 64 + sw8,
             (char*)sK + r * 4096 + wave * 1024);
      GLDS16(gv + (size_t)(r * 16 + (tid >> 4)) * 2048 + sw16,
             (char*)sV + r * 4096 + wave * 1024);
    }
    __syncthreads();  // staged data visible

    // S^T tiles: st[nt] covers kv rows nt*16 + lq*4 + r, q col = lr
    f32x4 st[8];
#pragma unroll
    for (int nt = 0; nt < 8; ++nt) {
      f16x8 kf0 =
          *(const f16x8*)&sK[(nt * 16 + lr) * 64 + ((lq ^ lr7) * 8)];
      f16x8 kf1 =
          *(const f16x8*)&sK[(nt * 16 + lr) * 64 + (((4 + lq) ^ lr7) * 8)];
      f32x4 s = {0.f, 0.f, 0.f, 0.f};
      s = __builtin_amdgcn_mfma_f32_16x16x32_f16(kf0, qf0, s, 0, 0, 0);
      s = __builtin_amdgcn_mfma_f32_16x16x32_f16(kf1, qf1, s, 0, 0, 0);
      st[nt] = s;
    }

    // online softmax (log2 domain), per q-column = per lane-group {lr,+16,+32,+48}
    float mloc = -__builtin_inff();
#pragma unroll
    for (int nt = 0; nt < 8; ++nt)
#pragma unroll
      for (int r = 0; r < 4; ++r) mloc = fmaxf(mloc, st[nt][r]);
    mloc *= sc;
    mloc = fmaxf(mloc, __shfl_xor(mloc, 16));
    mloc = fmaxf(mloc, __shfl_xor(mloc, 32));
    float mnew = fmaxf(m_i, mloc);
    float alpha = exp2f(m_i - mnew);
    float lsum = 0.f;
    f16x4 pf[8];
#pragma unroll
    for (int nt = 0; nt < 8; ++nt) {
#pragma unroll
      for (int r = 0; r < 4; ++r) {
        float p = exp2f(st[nt][r] * sc - mnew);
        lsum += p;
        pf[nt][r] = (f16)p;
      }
    }
    lsum += __shfl_xor(lsum, 16);
    lsum += __shfl_xor(lsum, 32);
    l_i = l_i * alpha + lsum;
    m_i = mnew;
#pragma unroll
    for (int d = 0; d < 4; ++d) ot[d] *= alpha;

    // O^T += V^T · P^T  (A-frag from sV, B-frag = pf from registers)
#pragma unroll
    for (int d = 0; d < 4; ++d)
#pragma unroll
      for (int ks = 0; ks < 8; ++ks) {
        int vslot = (ks * 2 + (lq >> 1)) ^ lr;  // granule xor, row&15 == lr
        f16x4 vf = *(const f16x4*)&sV[(d * 16 + lr) * 128 + vslot * 8 +
                                      (lq & 1) * 4];
        ot[d] = __builtin_amdgcn_mfma_f32_16x16x16f16(vf, pf[ks], ot[d], 0, 0, 0);
      }
  }

  // epilogue: O[q][c] = ot[d][r] / l,  c = d*16 + lq*4 + r (contiguous in r)
  float rl = 1.f / l_i;
  int b = bh >> 4, h = bh & 15;
  int t = qt * 64 + wave * 16 + lr;
  f16* gout = Op + ((size_t)(b * 2048 + t)) * 1024 + h * 64;
#pragma unroll
  for (int d = 0; d < 4; ++d) {
    f16x4 o;
#pragma unroll
    for (int r = 0; r < 4; ++r) o[r] = (f16)(ot[d][r] * rl);
    *(f16x4*)&gout[d * 16 + lq * 4] = o;
  }
}

// ---------------- launch ----------------
extern "C" void kernel_launch(void* const* d_in, const int* in_sizes, int n_in,
                              void* d_out, int out_size, void* d_ws,
                              size_t ws_size, hipStream_t stream) {
  const float* x     = (const float*)d_in[0];  // (2,2048,1024)
  const float* rope  = (const float*)d_in[1];  // (2048,512,2)
  const float* wqkv  = (const float*)d_in[2];  // (3072,1024)
  const float* wproj = (const float*)d_in[3];  // (1024,1024)
  float* out = (float*)d_out;                  // (2,2048,1024) fp32

  char* w = (char*)d_ws;
  const size_t MB = 1024 * 1024;
  f16* xh   = (f16*)(w + 0);        // 8 MB (dead after gemm1)
  f16* qh   = (f16*)(w + 0);        // 8 MB (reuses xh region)
  f16* wqh  = (f16*)(w + 8 * MB);   // 6 MB
  f16* wph  = (f16*)(w + 14 * MB);  // 2 MB
  f16* qkvh = (f16*)(w + 16 * MB);  // 24 MB (dead after rope/transpv)
  f16* aoh  = (f16*)(w + 16 * MB);  // 8 MB (reuses qkvh region)
  f16* kh   = (f16*)(w + 40 * MB);  // 8 MB
  f16* vth  = (f16*)(w + 48 * MB);  // 8 MB  -> total 56 MB

  k_cast<<<4096, 256, 0, stream>>>(x, xh, 1048576);
  k_cast<<<3072, 256, 0, stream>>>(wqkv, wqh, 786432);
  k_cast<<<1024, 256, 0, stream>>>(wproj, wph, 262144);

  // qkv = x @ w_qkv^T : (4096,3072) f16
  k_gemm_bt<<<dim3(32, 24), 256, 0, stream>>>(xh, wqh, (void*)qkvh, 4096, 3072,
                                              1024, 1);
  // rope + head split q,k ; transpose v
  k_rope<<<16384, 256, 0, stream>>>(qkvh, rope, qh, kh);
  k_transpv<<<1024, 256, 0, stream>>>(qkvh, vth);

  // attention -> (B,T,H*64) f16
  k_attn<<<dim3(32, 32), 256, 0, stream>>>(qh, kh, vth, aoh);

  // out = attn @ w_proj^T : (4096,1024) fp32
  k_gemm_bt<<<dim3(32, 8), 256, 0, stream>>>(aoh, wph, (void*)out, 4096, 1024,
                                             1024, 0);
}

// Round 4
// 202.597 us; speedup vs baseline: 2.1333x; 1.1913x over previous
//
#include <hip/hip_runtime.h>

typedef _Float16 f16;
typedef _Float16 f16x2 __attribute__((ext_vector_type(2)));
typedef _Float16 f16x4 __attribute__((ext_vector_type(4)));
typedef _Float16 f16x8 __attribute__((ext_vector_type(8)));
typedef float    f32x2 __attribute__((ext_vector_type(2)));
typedef float    f32x4 __attribute__((ext_vector_type(4)));

// async global->LDS, 16B per lane; LDS dest = wave-uniform base + lane*16
#define GLDS16(gptr, lptr)                                                     \
  __builtin_amdgcn_global_load_lds(                                            \
      (const __attribute__((address_space(1))) void*)(gptr),                   \
      (__attribute__((address_space(3))) void*)(lptr), 16, 0, 0)

// ---------------- fp32 -> f16 cast (vectorized) ----------------
__global__ __launch_bounds__(256) void k_cast(const float* __restrict__ in,
                                              f16* __restrict__ out, int n4) {
  int i = blockIdx.x * 256 + threadIdx.x;
  if (i >= n4) return;
  f32x4 v = ((const f32x4*)in)[i];
  f16x4 h;
  h[0] = (f16)v[0]; h[1] = (f16)v[1]; h[2] = (f16)v[2]; h[3] = (f16)v[3];
  ((f16x4*)out)[i] = h;
}

// ---------------- GEMM  C[M,N] = A[M,K] * B[N,K]^T  (both row-major f16) ----
// 128x128 tile / 4 waves (2x2), BK=64 (16 K-iters at K=1024 -> fewer barriers)
// LDS rows = 64 f16 = 8 granules of 16B; granule g of row r at slot g^(r&7).
__global__ __launch_bounds__(256, 4) void k_gemm_bt(const f16* __restrict__ A,
                                                    const f16* __restrict__ B,
                                                    void* __restrict__ Cout,
                                                    int M, int N, int K,
                                                    int out_is_f16) {
  __shared__ f16 sA[128 * 64];
  __shared__ f16 sB[128 * 64];
  const int tid = threadIdx.x;
  const int wave = tid >> 6, lane = tid & 63;
  const int lr = lane & 15, lq = lane >> 4;
  const int lr7 = lr & 7;
  const int wm = (wave >> 1) * 64, wn = (wave & 1) * 64;
  const size_t m0 = (size_t)blockIdx.x * 128, n0 = (size_t)blockIdx.y * 128;

  f32x4 acc[4][4] = {};

  // staging: lane -> LDS (row = r*32 + tid>>3, slot g' = tid&7);
  // fetch global granule g = g' ^ (row&7) = (tid&7) ^ ((tid>>3)&7)
  const int sw8 = ((tid & 7) ^ ((tid >> 3) & 7)) * 8;
  const f16* ga = A + (m0 + (tid >> 3)) * (size_t)K + sw8;
  const f16* gb = B + (n0 + (tid >> 3)) * (size_t)K + sw8;

  for (int k0 = 0; k0 < K; k0 += 64) {
    __syncthreads();  // previous iter's LDS reads complete
#pragma unroll
    for (int r = 0; r < 4; ++r) {
      GLDS16(ga + (size_t)(r * 32) * K + k0, (char*)sA + r * 4096 + wave * 1024);
      GLDS16(gb + (size_t)(r * 32) * K + k0, (char*)sB + r * 4096 + wave * 1024);
    }
    __syncthreads();  // staged data visible

#pragma unroll
    for (int kk = 0; kk < 2; ++kk) {
      f16x8 af[4], bf[4];
#pragma unroll
      for (int i = 0; i < 4; ++i)
        af[i] = *(const f16x8*)&sA[(wm + i * 16 + lr) * 64 +
                                   (((kk * 4 + lq) ^ lr7) * 8)];
#pragma unroll
      for (int j = 0; j < 4; ++j)
        bf[j] = *(const f16x8*)&sB[(wn + j * 16 + lr) * 64 +
                                   (((kk * 4 + lq) ^ lr7) * 8)];
#pragma unroll
      for (int i = 0; i < 4; ++i)
#pragma unroll
        for (int j = 0; j < 4; ++j)
          acc[i][j] = __builtin_amdgcn_mfma_f32_16x16x32_f16(af[i], bf[j],
                                                             acc[i][j], 0, 0, 0);
    }
  }

  // epilogue: C layout col=lane&15, row=quad*4+reg
  if (out_is_f16) {
    f16* C = (f16*)Cout;
#pragma unroll
    for (int i = 0; i < 4; ++i)
#pragma unroll
      for (int j = 0; j < 4; ++j)
#pragma unroll
        for (int r = 0; r < 4; ++r)
          C[(m0 + wm + i * 16 + lq * 4 + r) * (size_t)N + n0 + wn + j * 16 + lr] =
              (f16)acc[i][j][r];
  } else {
    float* C = (float*)Cout;
#pragma unroll
    for (int i = 0; i < 4; ++i)
#pragma unroll
      for (int j = 0; j < 4; ++j)
#pragma unroll
        for (int r = 0; r < 4; ++r)
          C[(m0 + wm + i * 16 + lq * 4 + r) * (size_t)N + n0 + wn + j * 16 + lr] =
              acc[i][j][r];
  }
}

// ---------------- RoPE + head-split for Q,K -> (B,H,T,64) f16 ----------------
// Q additionally scaled by 1/sqrt(dk)*log2(e) so attention works in exp2 domain.
__global__ __launch_bounds__(256) void k_rope(const f16* __restrict__ qkv,
                                              const float* __restrict__ rope,
                                              f16* __restrict__ qh,
                                              f16* __restrict__ kh) {
  int idx = blockIdx.x * 256 + threadIdx.x;  // b*2^21 + t*1024 + pair
  int pair = idx & 1023, t = (idx >> 10) & 2047, b = idx >> 21;
  int which = pair >> 9, p = pair & 511;
  const f16* src = qkv + ((size_t)(b * 2048 + t)) * 3072 + which * 1024 + p * 2;
  f16x2 s2 = *(const f16x2*)src;
  float xr = (float)s2[0], xi = (float)s2[1];
  f32x2 cs = *(const f32x2*)(rope + ((size_t)t * 512 + p) * 2);
  float scl = which ? 1.0f : 0.125f * 1.44269504088896f;
  float rr = (xr * cs[0] - xi * cs[1]) * scl;
  float ri = (xr * cs[1] + xi * cs[0]) * scl;
  int h = p >> 5, cc = (p & 31) * 2;
  f16* dst = (which ? kh : qh) + ((size_t)(b * 16 + h) * 2048 + t) * 64 + cc;
  f16x2 o; o[0] = (f16)rr; o[1] = (f16)ri;
  *(f16x2*)dst = o;
}

// ---------------- V transpose-cast -> (B,H,64,T) f16 ----------------
__global__ __launch_bounds__(256) void k_transpv(const f16* __restrict__ qkv,
                                                 f16* __restrict__ vt) {
  int bh = blockIdx.x >> 5, tt = blockIdx.x & 31;
  int b = bh >> 4, h = bh & 15;
  __shared__ f16 tile[64][65];
  int tid = threadIdx.x;
  int r = tid >> 4, c4 = (tid & 15) * 4;
#pragma unroll
  for (int rr = 0; rr < 4; ++rr) {
    int row = rr * 16 + r;  // t within tile
    const f16* src =
        qkv + ((size_t)(b * 2048 + tt * 64 + row)) * 3072 + 2048 + h * 64 + c4;
    f16x4 v = *(const f16x4*)src;
    tile[row][c4 + 0] = v[0]; tile[row][c4 + 1] = v[1];
    tile[row][c4 + 2] = v[2]; tile[row][c4 + 3] = v[3];
  }
  __syncthreads();
#pragma unroll
  for (int rr = 0; rr < 4; ++rr) {
    int c = rr * 16 + r;          // dk col
    int t4 = (tid & 15) * 4;      // t within tile
    f16x4 o;
    o[0] = tile[t4 + 0][c]; o[1] = tile[t4 + 1][c];
    o[2] = tile[t4 + 2][c]; o[3] = tile[t4 + 3][c];
    *(f16x4*)(vt + ((size_t)(bh * 64 + c)) * 2048 + tt * 64 + t4) = o;
  }
}

// ---------------- Flash attention (online-max softmax, 128-q tile) ---------
// block: one (bh, 128-row q-tile); wave w owns q cols [w*32,+32) as two
// 16-wide fragments (a: +lr, b: +16+lr). S^T = K·Q^T (mfma 16x16x32, C rows=kv
// cols=q); Q pre-scaled by 1/sqrt(dk)*log2e so P = exp2(S - m). Online max IS
// REQUIRED here: rope factors are N(0,1) (not unit rotations) -> score tails
// reach exp2 args > 16 which overflow f16 (round-3 NaN post-mortem).
// P^T (C-layout) feeds mfma_16x16x16f16 B-operand directly; K/V fragments
// loaded once per chunk serve both q-fragments. l cross-lane reduction
// deferred to epilogue.
// LDS swizzle: sQ/sK rows = 64 f16 = 8 granules, slot = g ^ (row&7);
//              sV  rows = 128 f16 = 16 granules, slot = g ^ (row&15).
__global__ __launch_bounds__(256, 3) void k_attn(const f16* __restrict__ Qp,
                                                 const f16* __restrict__ Kp,
                                                 const f16* __restrict__ Vt,
                                                 f16* __restrict__ Op) {
  __shared__ f16 sQ[128 * 64];   // 16 KB
  __shared__ f16 sK[128 * 64];   // 16 KB
  __shared__ f16 sV[64 * 128];   // 16 KB  (dk-major: sV[c*128 + t])
  const int tid = threadIdx.x, wave = tid >> 6, lane = tid & 63;
  const int lr = lane & 15, lq = lane >> 4;
  const int lr7 = lr & 7;
  const int bh = blockIdx.x, qt = blockIdx.y;
  const size_t base = (size_t)bh * 2048 * 64;

  // staging swizzle offsets (in f16 elements)
  const int sw8 = ((tid & 7) ^ ((tid >> 3) & 7)) * 8;    // sQ/sK granule xor
  const int sw16 = ((tid & 15) ^ ((tid >> 4) & 15)) * 8; // sV granule xor

  // stage Q tile: rows qt*128 .. +128
  const f16* gq = Qp + base + (size_t)qt * 128 * 64;
#pragma unroll
  for (int r = 0; r < 4; ++r)
    GLDS16(gq + (size_t)(r * 32 + (tid >> 3)) * 64 + sw8,
           (char*)sQ + r * 4096 + wave * 1024);
  __syncthreads();
  f16x8 qa0 = *(const f16x8*)&sQ[(wave * 32 + lr) * 64 + ((lq ^ lr7) * 8)];
  f16x8 qa1 = *(const f16x8*)&sQ[(wave * 32 + lr) * 64 + (((4 + lq) ^ lr7) * 8)];
  f16x8 qb0 = *(const f16x8*)&sQ[(wave * 32 + 16 + lr) * 64 + ((lq ^ lr7) * 8)];
  f16x8 qb1 =
      *(const f16x8*)&sQ[(wave * 32 + 16 + lr) * 64 + (((4 + lq) ^ lr7) * 8)];

  f32x4 ota[4] = {}, otb[4] = {};
  float ma = -__builtin_inff(), mb = -__builtin_inff();
  float la = 0.f, lb = 0.f;

  for (int jc = 0; jc < 16; ++jc) {
    __syncthreads();  // previous chunk's LDS reads done
    const f16* gk = Kp + base + (size_t)jc * 128 * 64;
    const f16* gv = Vt + base + (size_t)jc * 128;
#pragma unroll
    for (int r = 0; r < 4; ++r) {
      GLDS16(gk + (size_t)(r * 32 + (tid >> 3)) * 64 + sw8,
             (char*)sK + r * 4096 + wave * 1024);
      GLDS16(gv + (size_t)(r * 16 + (tid >> 4)) * 2048 + sw16,
             (char*)sV + r * 4096 + wave * 1024);
    }
    __syncthreads();  // staged data visible

    // S^T tiles (Q pre-scaled, so these are already log2-domain scores)
    f32x4 sta[8], stb[8];
#pragma unroll
    for (int nt = 0; nt < 8; ++nt) {
      f16x8 kf0 = *(const f16x8*)&sK[(nt * 16 + lr) * 64 + ((lq ^ lr7) * 8)];
      f16x8 kf1 =
          *(const f16x8*)&sK[(nt * 16 + lr) * 64 + (((4 + lq) ^ lr7) * 8)];
      f32x4 z = {0.f, 0.f, 0.f, 0.f};
      f32x4 sa = __builtin_amdgcn_mfma_f32_16x16x32_f16(kf0, qa0, z, 0, 0, 0);
      sta[nt] = __builtin_amdgcn_mfma_f32_16x16x32_f16(kf1, qa1, sa, 0, 0, 0);
      f32x4 sb = __builtin_amdgcn_mfma_f32_16x16x32_f16(kf0, qb0, z, 0, 0, 0);
      stb[nt] = __builtin_amdgcn_mfma_f32_16x16x32_f16(kf1, qb1, sb, 0, 0, 0);
    }

    // chunk max per q column (cross the 4 lq lanes holding the same q)
    float mla = -__builtin_inff(), mlb = -__builtin_inff();
#pragma unroll
    for (int nt = 0; nt < 8; ++nt)
#pragma unroll
      for (int r = 0; r < 4; ++r) {
        mla = fmaxf(mla, sta[nt][r]);
        mlb = fmaxf(mlb, stb[nt][r]);
      }
    mla = fmaxf(mla, __shfl_xor(mla, 16));
    mla = fmaxf(mla, __shfl_xor(mla, 32));
    mlb = fmaxf(mlb, __shfl_xor(mlb, 16));
    mlb = fmaxf(mlb, __shfl_xor(mlb, 32));
    float mna = fmaxf(ma, mla), mnb = fmaxf(mb, mlb);
    float aa = __builtin_amdgcn_exp2f(ma - mna);
    float ab = __builtin_amdgcn_exp2f(mb - mnb);
    ma = mna; mb = mnb;
    la *= aa; lb *= ab;

    f16x4 pfa[8], pfb[8];
#pragma unroll
    for (int nt = 0; nt < 8; ++nt) {
#pragma unroll
      for (int r = 0; r < 4; ++r) {
        float pa = __builtin_amdgcn_exp2f(sta[nt][r] - mna);
        float pb = __builtin_amdgcn_exp2f(stb[nt][r] - mnb);
        la += pa; lb += pb;
        pfa[nt][r] = (f16)pa; pfb[nt][r] = (f16)pb;
      }
    }
#pragma unroll
    for (int d = 0; d < 4; ++d) { ota[d] *= aa; otb[d] *= ab; }

    // O^T += V^T · P^T  (V fragment loaded once, used for both q-frags)
#pragma unroll
    for (int d = 0; d < 4; ++d)
#pragma unroll
      for (int ks = 0; ks < 8; ++ks) {
        int vslot = (ks * 2 + (lq >> 1)) ^ lr;  // granule xor, row&15 == lr
        f16x4 vf = *(const f16x4*)&sV[(d * 16 + lr) * 128 + vslot * 8 +
                                      (lq & 1) * 4];
        ota[d] = __builtin_amdgcn_mfma_f32_16x16x16f16(vf, pfa[ks], ota[d],
                                                       0, 0, 0);
        otb[d] = __builtin_amdgcn_mfma_f32_16x16x16f16(vf, pfb[ks], otb[d],
                                                       0, 0, 0);
      }
  }

  // epilogue: reduce l across lq groups once; O[q][c] = ot[d][r] / l
  la += __shfl_xor(la, 16); la += __shfl_xor(la, 32);
  lb += __shfl_xor(lb, 16); lb += __shfl_xor(lb, 32);
  float rla = 1.f / la, rlb = 1.f / lb;
  int b = bh >> 4, h = bh & 15;
  int ta = qt * 128 + wave * 32 + lr;
  f16* gouta = Op + ((size_t)(b * 2048 + ta)) * 1024 + h * 64;
  f16* goutb = gouta + (size_t)16 * 1024;
#pragma unroll
  for (int d = 0; d < 4; ++d) {
    f16x4 oa, ob;
#pragma unroll
    for (int r = 0; r < 4; ++r) {
      oa[r] = (f16)(ota[d][r] * rla);
      ob[r] = (f16)(otb[d][r] * rlb);
    }
    *(f16x4*)&gouta[d * 16 + lq * 4] = oa;
    *(f16x4*)&goutb[d * 16 + lq * 4] = ob;
  }
}

// ---------------- launch ----------------
extern "C" void kernel_launch(void* const* d_in, const int* in_sizes, int n_in,
                              void* d_out, int out_size, void* d_ws,
                              size_t ws_size, hipStream_t stream) {
  const float* x     = (const float*)d_in[0];  // (2,2048,1024)
  const float* rope  = (const float*)d_in[1];  // (2048,512,2)
  const float* wqkv  = (const float*)d_in[2];  // (3072,1024)
  const float* wproj = (const float*)d_in[3];  // (1024,1024)
  float* out = (float*)d_out;                  // (2,2048,1024) fp32

  char* w = (char*)d_ws;
  const size_t MB = 1024 * 1024;
  f16* xh   = (f16*)(w + 0);        // 8 MB (dead after gemm1)
  f16* qh   = (f16*)(w + 0);        // 8 MB (reuses xh region)
  f16* wqh  = (f16*)(w + 8 * MB);   // 6 MB
  f16* wph  = (f16*)(w + 14 * MB);  // 2 MB
  f16* qkvh = (f16*)(w + 16 * MB);  // 24 MB (dead after rope/transpv)
  f16* aoh  = (f16*)(w + 16 * MB);  // 8 MB (reuses qkvh region)
  f16* kh   = (f16*)(w + 40 * MB);  // 8 MB
  f16* vth  = (f16*)(w + 48 * MB);  // 8 MB  -> total 56 MB

  k_cast<<<4096, 256, 0, stream>>>(x, xh, 1048576);
  k_cast<<<3072, 256, 0, stream>>>(wqkv, wqh, 786432);
  k_cast<<<1024, 256, 0, stream>>>(wproj, wph, 262144);

  // qkv = x @ w_qkv^T : (4096,3072) f16
  k_gemm_bt<<<dim3(32, 24), 256, 0, stream>>>(xh, wqh, (void*)qkvh, 4096, 3072,
                                              1024, 1);
  // rope + head split q,k ; transpose v
  k_rope<<<16384, 256, 0, stream>>>(qkvh, rope, qh, kh);
  k_transpv<<<1024, 256, 0, stream>>>(qkvh, vth);

  // attention -> (B,T,H*64) f16
  k_attn<<<dim3(32, 16), 256, 0, stream>>>(qh, kh, vth, aoh);

  // out = attn @ w_proj^T : (4096,1024) fp32
  k_gemm_bt<<<dim3(32, 8), 256, 0, stream>>>(aoh, wph, (void*)out, 4096, 1024,
                                             1024, 0);
}

// Round 5
// 186.535 us; speedup vs baseline: 2.3170x; 1.0861x over previous
//
#include <hip/hip_runtime.h>

typedef _Float16 f16;
typedef _Float16 f16x2 __attribute__((ext_vector_type(2)));
typedef _Float16 f16x4 __attribute__((ext_vector_type(4)));
typedef _Float16 f16x8 __attribute__((ext_vector_type(8)));
typedef float    f32x2 __attribute__((ext_vector_type(2)));
typedef float    f32x4 __attribute__((ext_vector_type(4)));

// async global->LDS, 16B per lane; LDS dest = wave-uniform base + lane*16
#define GLDS16(gptr, lptr)                                                     \
  __builtin_amdgcn_global_load_lds(                                            \
      (const __attribute__((address_space(1))) void*)(gptr),                   \
      (__attribute__((address_space(3))) void*)(lptr), 16, 0, 0)

// raw barrier/waitcnt: keep prefetch loads in flight across barriers
// (the HIP __syncthreads() would drain vmcnt(0) and serialize the pipeline)
#define S_BARRIER() __builtin_amdgcn_s_barrier()
#define FENCE() asm volatile("" ::: "memory")
#define WAIT_VM8() asm volatile("s_waitcnt vmcnt(8)" ::: "memory")
#define WAIT_VM0() asm volatile("s_waitcnt vmcnt(0)" ::: "memory")
#define WAIT_LGKM0() asm volatile("s_waitcnt lgkmcnt(0)" ::: "memory")

// ---------------- fused fp32 -> f16 cast of x, w_qkv, w_proj ----------------
__global__ __launch_bounds__(256) void k_cast3(const float* __restrict__ a,
                                               const float* __restrict__ b,
                                               const float* __restrict__ c,
                                               f16* __restrict__ oa,
                                               f16* __restrict__ ob,
                                               f16* __restrict__ oc) {
  int i = blockIdx.x * 256 + threadIdx.x;  // [0, 2097152)
  const float* src;
  f16* dst;
  int off;
  if (i < 1048576) { src = a; dst = oa; off = i; }
  else if (i < 1835008) { src = b; dst = ob; off = i - 1048576; }
  else { src = c; dst = oc; off = i - 1835008; }
  f32x4 v = ((const f32x4*)src)[off];
  f16x4 h;
  h[0] = (f16)v[0]; h[1] = (f16)v[1]; h[2] = (f16)v[2]; h[3] = (f16)v[3];
  ((f16x4*)dst)[off] = h;
}

// ---------------- GEMM1 fused: qkv = x@w^T, epilogue does RoPE+split+Vt ------
// 128x128 tile / 4 waves (2x2), BK=64. M=4096 (rows=b*2048+t), N=3072, K=1024.
// n-region (uniform/block): [0,1024)=Q (rope, *1/8*log2e), [1024,2048)=K (rope),
// [2048,3072)=V (transposed store). Rope pairs (2p,2p+1) live in lane lr and
// lr^1 of the C-fragment -> one shfl_xor(v,1) gives each lane (xr,xi).
// LDS rows = 64 f16 = 8 granules of 16B; granule g of row r at slot g^(r&7).
__global__ __launch_bounds__(256, 4) void k_gemm_qkv(
    const f16* __restrict__ A, const f16* __restrict__ B,
    const float* __restrict__ rope, f16* __restrict__ qh,
    f16* __restrict__ kh, f16* __restrict__ vt) {
  const int K = 1024;
  __shared__ f16 sA[128 * 64];
  __shared__ f16 sB[128 * 64];
  const int tid = threadIdx.x;
  const int wave = tid >> 6, lane = tid & 63;
  const int lr = lane & 15, lq = lane >> 4;
  const int lr7 = lr & 7;
  const int wm = (wave >> 1) * 64, wn = (wave & 1) * 64;
  const size_t m0 = (size_t)blockIdx.x * 128, n0 = (size_t)blockIdx.y * 128;

  f32x4 acc[4][4] = {};

  const int sw8 = ((tid & 7) ^ ((tid >> 3) & 7)) * 8;
  const f16* ga = A + (m0 + (tid >> 3)) * (size_t)K + sw8;
  const f16* gb = B + (n0 + (tid >> 3)) * (size_t)K + sw8;

  for (int k0 = 0; k0 < K; k0 += 64) {
    __syncthreads();
#pragma unroll
    for (int r = 0; r < 4; ++r) {
      GLDS16(ga + (size_t)(r * 32) * K + k0, (char*)sA + r * 4096 + wave * 1024);
      GLDS16(gb + (size_t)(r * 32) * K + k0, (char*)sB + r * 4096 + wave * 1024);
    }
    __syncthreads();

#pragma unroll
    for (int kk = 0; kk < 2; ++kk) {
      f16x8 af[4], bf[4];
#pragma unroll
      for (int i = 0; i < 4; ++i)
        af[i] = *(const f16x8*)&sA[(wm + i * 16 + lr) * 64 +
                                   (((kk * 4 + lq) ^ lr7) * 8)];
#pragma unroll
      for (int j = 0; j < 4; ++j)
        bf[j] = *(const f16x8*)&sB[(wn + j * 16 + lr) * 64 +
                                   (((kk * 4 + lq) ^ lr7) * 8)];
#pragma unroll
      for (int i = 0; i < 4; ++i)
#pragma unroll
        for (int j = 0; j < 4; ++j)
          acc[i][j] = __builtin_amdgcn_mfma_f32_16x16x32_f16(af[i], bf[j],
                                                             acc[i][j], 0, 0, 0);
    }
  }

  // ---- fused epilogue (C layout: col=lane&15, row=quad*4+reg) ----
  const int region = (int)(n0 >> 10);  // 0=Q 1=K 2=V, uniform per block
  if (region == 2) {
    // V: C[m][e] -> vt[(bh*64 + c)*2048 + t], 4 consecutive t per lane
#pragma unroll
    for (int i = 0; i < 4; ++i)
#pragma unroll
      for (int j = 0; j < 4; ++j) {
        int e = (int)(n0 + wn + j * 16 + lr) - 2048;
        int h = e >> 6, c = e & 63;
        int m = (int)(m0 + wm + i * 16 + lq * 4);
        int b = m >> 11, t0 = m & 2047;
        f16x4 o;
#pragma unroll
        for (int r = 0; r < 4; ++r) o[r] = (f16)acc[i][j][r];
        *(f16x4*)&vt[(((size_t)(b * 16 + h)) * 64 + c) * 2048 + t0] = o;
      }
  } else {
    const float scl = region == 0 ? 0.1803368801111204f : 1.0f;  // 1/8*log2e
    f16* dst = region == 0 ? qh : kh;
    const int odd = lr & 1;
#pragma unroll
    for (int i = 0; i < 4; ++i)
#pragma unroll
      for (int j = 0; j < 4; ++j) {
        int e = ((int)(n0 + wn + j * 16 + lr)) & 1023;
        int h = e >> 6, c = e & 63, p = e >> 1;
        int mb = (int)(m0 + wm + i * 16 + lq * 4);
        int b = mb >> 11;
#pragma unroll
        for (int r = 0; r < 4; ++r) {
          int t = (mb + r) & 2047;
          float v = acc[i][j][r];
          float partner = __shfl_xor(v, 1);
          f32x2 cs = *(const f32x2*)&rope[((size_t)t * 512 + p) * 2];
          // even lane: v=xr, partner=xi -> rotr = xr*cos - xi*sin
          // odd  lane: v=xi, partner=xr -> roti = xr*sin + xi*cos
          float out = odd ? (partner * cs[1] + v * cs[0])
                          : (v * cs[0] - partner * cs[1]);
          dst[(((size_t)(b * 16 + h)) * 2048 + t) * 64 + c] = (f16)(out * scl);
        }
      }
  }
}

// ---------------- GEMM2  C[M,N] = A[M,K] * B[N,K]^T, fp32 out ----------------
__global__ __launch_bounds__(256, 4) void k_gemm_bt(const f16* __restrict__ A,
                                                    const f16* __restrict__ B,
                                                    float* __restrict__ C,
                                                    int M, int N, int K) {
  __shared__ f16 sA[128 * 64];
  __shared__ f16 sB[128 * 64];
  const int tid = threadIdx.x;
  const int wave = tid >> 6, lane = tid & 63;
  const int lr = lane & 15, lq = lane >> 4;
  const int lr7 = lr & 7;
  const int wm = (wave >> 1) * 64, wn = (wave & 1) * 64;
  const size_t m0 = (size_t)blockIdx.x * 128, n0 = (size_t)blockIdx.y * 128;

  f32x4 acc[4][4] = {};

  const int sw8 = ((tid & 7) ^ ((tid >> 3) & 7)) * 8;
  const f16* ga = A + (m0 + (tid >> 3)) * (size_t)K + sw8;
  const f16* gb = B + (n0 + (tid >> 3)) * (size_t)K + sw8;

  for (int k0 = 0; k0 < K; k0 += 64) {
    __syncthreads();
#pragma unroll
    for (int r = 0; r < 4; ++r) {
      GLDS16(ga + (size_t)(r * 32) * K + k0, (char*)sA + r * 4096 + wave * 1024);
      GLDS16(gb + (size_t)(r * 32) * K + k0, (char*)sB + r * 4096 + wave * 1024);
    }
    __syncthreads();

#pragma unroll
    for (int kk = 0; kk < 2; ++kk) {
      f16x8 af[4], bf[4];
#pragma unroll
      for (int i = 0; i < 4; ++i)
        af[i] = *(const f16x8*)&sA[(wm + i * 16 + lr) * 64 +
                                   (((kk * 4 + lq) ^ lr7) * 8)];
#pragma unroll
      for (int j = 0; j < 4; ++j)
        bf[j] = *(const f16x8*)&sB[(wn + j * 16 + lr) * 64 +
                                   (((kk * 4 + lq) ^ lr7) * 8)];
#pragma unroll
      for (int i = 0; i < 4; ++i)
#pragma unroll
        for (int j = 0; j < 4; ++j)
          acc[i][j] = __builtin_amdgcn_mfma_f32_16x16x32_f16(af[i], bf[j],
                                                             acc[i][j], 0, 0, 0);
    }
  }

#pragma unroll
  for (int i = 0; i < 4; ++i)
#pragma unroll
    for (int j = 0; j < 4; ++j)
#pragma unroll
      for (int r = 0; r < 4; ++r)
        C[(m0 + wm + i * 16 + lq * 4 + r) * (size_t)N + n0 + wn + j * 16 + lr] =
            acc[i][j][r];
}

// ---------------- Flash attention (online-max, 128-q tile, dbuf K/V) --------
// block: one (bh, 128-row q-tile); wave w owns q cols [w*32,+32) as two
// 16-wide fragments. S^T = K·Q^T (16x16x32, C rows=kv cols=q); Q pre-scaled by
// 1/sqrt(dk)*log2e -> P = exp2(S-m), online max REQUIRED (rope factors are
// N(0,1), heavy score tails overflow f16 without it — round-3 post-mortem).
// P^T C-layout == 16x16x16 B-operand layout -> PV direct from registers.
// K/V double-buffered in LDS; raw s_barrier + s_waitcnt vmcnt(8) keeps the
// next chunk's 8 global_load_lds in flight across the barrier (no vmcnt(0)
// drain). Per-wave per-chunk: 8 GLDS; wait vmcnt(8) = wait only the previous
// chunk's 8. End-of-chunk barrier (after lgkmcnt(0)) protects the buffer that
// iteration jc+1 overwrites.
// LDS swizzle: sQ/K rows=64 f16: slot g^(row&7); V rows=128 f16: g^(row&15).
__global__ __launch_bounds__(256, 2) void k_attn(const f16* __restrict__ Qp,
                                                 const f16* __restrict__ Kp,
                                                 const f16* __restrict__ Vt,
                                                 f16* __restrict__ Op) {
  __shared__ f16 sQ[128 * 64];       // 16 KB
  __shared__ f16 sKV[2 * 16384];     // 2 x (K 16KB + V 16KB) = 64 KB
  const int tid = threadIdx.x, wave = tid >> 6, lane = tid & 63;
  const int lr = lane & 15, lq = lane >> 4;
  const int lr7 = lr & 7;
  const int bh = blockIdx.x, qt = blockIdx.y;
  const size_t base = (size_t)bh * 2048 * 64;

  const int sw8 = ((tid & 7) ^ ((tid >> 3) & 7)) * 8;    // K/Q granule xor
  const int sw16 = ((tid & 15) ^ ((tid >> 4) & 15)) * 8; // V granule xor

  auto stage_kv = [&](int jcc, int d) {
    const f16* gk = Kp + base + (size_t)jcc * 128 * 64;
    const f16* gv = Vt + base + (size_t)jcc * 128;
    char* bK = (char*)sKV + d * 32768;
    char* bV = bK + 16384;
#pragma unroll
    for (int r = 0; r < 4; ++r) {
      GLDS16(gk + (size_t)(r * 32 + (tid >> 3)) * 64 + sw8,
             bK + r * 4096 + wave * 1024);
      GLDS16(gv + (size_t)(r * 16 + (tid >> 4)) * 2048 + sw16,
             bV + r * 4096 + wave * 1024);
    }
  };

  // prologue: stage Q (4 loads/wave), then chunk0 (8 loads/wave)
  const f16* gq = Qp + base + (size_t)qt * 128 * 64;
#pragma unroll
  for (int r = 0; r < 4; ++r)
    GLDS16(gq + (size_t)(r * 32 + (tid >> 3)) * 64 + sw8,
           (char*)sQ + r * 4096 + wave * 1024);
  stage_kv(0, 0);
  WAIT_VM8();  // 12 outstanding -> wait oldest 4 (Q); chunk0 still in flight
  S_BARRIER();
  FENCE();
  f16x8 qa0 = *(const f16x8*)&sQ[(wave * 32 + lr) * 64 + ((lq ^ lr7) * 8)];
  f16x8 qa1 = *(const f16x8*)&sQ[(wave * 32 + lr) * 64 + (((4 + lq) ^ lr7) * 8)];
  f16x8 qb0 = *(const f16x8*)&sQ[(wave * 32 + 16 + lr) * 64 + ((lq ^ lr7) * 8)];
  f16x8 qb1 =
      *(const f16x8*)&sQ[(wave * 32 + 16 + lr) * 64 + (((4 + lq) ^ lr7) * 8)];

  f32x4 ota[4] = {}, otb[4] = {};
  float ma = -__builtin_inff(), mb = -__builtin_inff();
  float la = 0.f, lb = 0.f;

#pragma unroll 1
  for (int jc = 0; jc < 16; ++jc) {
    const int cur = jc & 1;
    if (jc < 15) {
      stage_kv(jc + 1, cur ^ 1);  // 16 outstanding
      WAIT_VM8();                 // wait chunk jc's 8; jc+1's 8 keep flying
    } else {
      WAIT_VM0();
    }
    S_BARRIER();  // all waves' chunk-jc loads complete
    FENCE();

    const f16* bK = (const f16*)((char*)sKV + cur * 32768);
    const f16* bV = bK + 8192;

    // S^T tiles (log2-domain scores)
    f32x4 sta[8], stb[8];
#pragma unroll
    for (int nt = 0; nt < 8; ++nt) {
      f16x8 kf0 = *(const f16x8*)&bK[(nt * 16 + lr) * 64 + ((lq ^ lr7) * 8)];
      f16x8 kf1 =
          *(const f16x8*)&bK[(nt * 16 + lr) * 64 + (((4 + lq) ^ lr7) * 8)];
      f32x4 z = {0.f, 0.f, 0.f, 0.f};
      f32x4 sa = __builtin_amdgcn_mfma_f32_16x16x32_f16(kf0, qa0, z, 0, 0, 0);
      sta[nt] = __builtin_amdgcn_mfma_f32_16x16x32_f16(kf1, qa1, sa, 0, 0, 0);
      f32x4 sb = __builtin_amdgcn_mfma_f32_16x16x32_f16(kf0, qb0, z, 0, 0, 0);
      stb[nt] = __builtin_amdgcn_mfma_f32_16x16x32_f16(kf1, qb1, sb, 0, 0, 0);
    }

    // online-max softmax per q column (4 lq lanes share a q)
    float mla = -__builtin_inff(), mlb = -__builtin_inff();
#pragma unroll
    for (int nt = 0; nt < 8; ++nt)
#pragma unroll
      for (int r = 0; r < 4; ++r) {
        mla = fmaxf(mla, sta[nt][r]);
        mlb = fmaxf(mlb, stb[nt][r]);
      }
    mla = fmaxf(mla, __shfl_xor(mla, 16));
    mla = fmaxf(mla, __shfl_xor(mla, 32));
    mlb = fmaxf(mlb, __shfl_xor(mlb, 16));
    mlb = fmaxf(mlb, __shfl_xor(mlb, 32));
    float mna = fmaxf(ma, mla), mnb = fmaxf(mb, mlb);
    float aa = __builtin_amdgcn_exp2f(ma - mna);
    float ab = __builtin_amdgcn_exp2f(mb - mnb);
    ma = mna; mb = mnb;
    la *= aa; lb *= ab;

    f16x4 pfa[8], pfb[8];
#pragma unroll
    for (int nt = 0; nt < 8; ++nt) {
#pragma unroll
      for (int r = 0; r < 4; ++r) {
        float pa = __builtin_amdgcn_exp2f(sta[nt][r] - mna);
        float pb = __builtin_amdgcn_exp2f(stb[nt][r] - mnb);
        la += pa; lb += pb;
        pfa[nt][r] = (f16)pa; pfb[nt][r] = (f16)pb;
      }
    }
#pragma unroll
    for (int d = 0; d < 4; ++d) { ota[d] *= aa; otb[d] *= ab; }

    // O^T += V^T · P^T  (V fragment loaded once, used for both q-frags)
#pragma unroll
    for (int d = 0; d < 4; ++d)
#pragma unroll
      for (int ks = 0; ks < 8; ++ks) {
        int vslot = (ks * 2 + (lq >> 1)) ^ lr;  // granule xor, row&15 == lr
        f16x4 vf = *(const f16x4*)&bV[(d * 16 + lr) * 128 + vslot * 8 +
                                      (lq & 1) * 4];
        ota[d] = __builtin_amdgcn_mfma_f32_16x16x16f16(vf, pfa[ks], ota[d],
                                                       0, 0, 0);
        otb[d] = __builtin_amdgcn_mfma_f32_16x16x16f16(vf, pfb[ks], otb[d],
                                                       0, 0, 0);
      }

    WAIT_LGKM0();  // this wave's reads of buf[cur] done
    S_BARRIER();   // all waves done -> safe for jc+1 to overwrite buf[cur]
    FENCE();
  }

  // epilogue: reduce l across lq groups once; O[q][c] = ot[d][r] / l
  la += __shfl_xor(la, 16); la += __shfl_xor(la, 32);
  lb += __shfl_xor(lb, 16); lb += __shfl_xor(lb, 32);
  float rla = 1.f / la, rlb = 1.f / lb;
  int b = bh >> 4, h = bh & 15;
  int ta = qt * 128 + wave * 32 + lr;
  f16* gouta = Op + ((size_t)(b * 2048 + ta)) * 1024 + h * 64;
  f16* goutb = gouta + (size_t)16 * 1024;
#pragma unroll
  for (int d = 0; d < 4; ++d) {
    f16x4 oa, ob;
#pragma unroll
    for (int r = 0; r < 4; ++r) {
      oa[r] = (f16)(ota[d][r] * rla);
      ob[r] = (f16)(otb[d][r] * rlb);
    }
    *(f16x4*)&gouta[d * 16 + lq * 4] = oa;
    *(f16x4*)&goutb[d * 16 + lq * 4] = ob;
  }
}

// ---------------- launch ----------------
extern "C" void kernel_launch(void* const* d_in, const int* in_sizes, int n_in,
                              void* d_out, int out_size, void* d_ws,
                              size_t ws_size, hipStream_t stream) {
  const float* x     = (const float*)d_in[0];  // (2,2048,1024)
  const float* rope  = (const float*)d_in[1];  // (2048,512,2)
  const float* wqkv  = (const float*)d_in[2];  // (3072,1024)
  const float* wproj = (const float*)d_in[3];  // (1024,1024)
  float* out = (float*)d_out;                  // (2,2048,1024) fp32

  char* w = (char*)d_ws;
  const size_t MB = 1024 * 1024;
  f16* xh  = (f16*)(w + 0);        // 8 MB
  f16* wqh = (f16*)(w + 8 * MB);   // 6 MB
  f16* wph = (f16*)(w + 14 * MB);  // 2 MB
  f16* qh  = (f16*)(w + 16 * MB);  // 8 MB
  f16* kh  = (f16*)(w + 24 * MB);  // 8 MB
  f16* vth = (f16*)(w + 32 * MB);  // 8 MB
  f16* aoh = (f16*)(w + 40 * MB);  // 8 MB  -> total 48 MB

  // all three casts in one dispatch
  k_cast3<<<8192, 256, 0, stream>>>(x, wqkv, wproj, xh, wqh, wph);

  // qkv GEMM with fused RoPE + head-split + V-transpose epilogue
  k_gemm_qkv<<<dim3(32, 24), 256, 0, stream>>>(xh, wqh, rope, qh, kh, vth);

  // attention -> (B,T,H*64) f16
  k_attn<<<dim3(32, 16), 256, 0, stream>>>(qh, kh, vth, aoh);

  // out = attn @ w_proj^T : (4096,1024) fp32
  k_gemm_bt<<<dim3(32, 8), 256, 0, stream>>>(aoh, wph, out, 4096, 1024, 1024);
}